// Round 1
// 244.294 us; speedup vs baseline: 1.0212x; 1.0212x over previous
//
#include <hip/hip_runtime.h>

// LaBramChannelPatcher: [B=16, W=32, T=1000, C=64] fp32 ->
//   patches [B, W, C*nt=320, P=200]  (== per-(b,w) transpose [T,C] -> [C,T])
//   channel_indices [320] = repeat(arange(64), 5)
//   time_indices    [320] = tile(arange(5), 64)
//
// Latency-bound transpose -> async staging version:
//  - Phase 1: __builtin_amdgcn_global_load_lds (16B DMA, fire-and-forget),
//    linear LDS dest (required), XOR-pre-swizzled GLOBAL source (rule #21).
//    Swizzle involution on 16B units: v <-> v ^ ((v>>6)&7)
//    (flips low 3 bits of the c4-unit index by the t-subblock index).
//  - Phase 2: same-swizzle ds_read_b32 column gather (banks spread ~8-way
//    per c-group instead of 1), coalesced float4 stores along t.

#define TDIM 1000
#define CDIM 64
#define TT   100        // t-rows per tile (1000 = 10 * 100)
#define NTILE 10
#define TILE_UNITS 1600          // TT*CDIM/4 16-byte units
#define PATCH_ELEMS 32768000     // 16*32*320*200

__device__ __forceinline__ void async_cp16(const char* g, char* l) {
    __builtin_amdgcn_global_load_lds(
        (const __attribute__((address_space(1))) void*)g,
        (__attribute__((address_space(3))) void*)l,
        16, 0, 0);
}

__global__ __launch_bounds__(256) void labram_patcher_kernel(
    const float* __restrict__ in, float* __restrict__ out)
{
    __shared__ float lds[TT * CDIM];   // linear [ti][c], content XOR-swizzled

    const int tid  = threadIdx.x;
    const int tile = blockIdx.x % NTILE;
    const int bw   = blockIdx.x / NTILE;   // 0..511  (b*32 + w)
    const int t0   = tile * TT;

    // ---- Phase 1: async global->LDS. Tile is a contiguous 25600B region of
    // the input; LDS unit v receives global unit (v ^ ((v>>6)&7)). All 6-7
    // loads per thread issue back-to-back; the only drain is the barrier. ----
    const char* gtile = (const char*)(in + (size_t)(bw * TDIM + t0) * CDIM);
    char* ltile = (char*)lds;

    #pragma unroll
    for (int k = 0; k < 6; ++k) {
        const int v = tid + k * 256;             // LDS 16B-unit index (linear)
        const int s = v ^ ((v >> 6) & 7);        // pre-swizzled source unit
        async_cp16(gtile + s * 16, ltile + v * 16);
    }
    if (tid < TILE_UNITS - 6 * 256) {            // tail units 1536..1599, wave 0
        const int v = tid + 6 * 256;
        const int s = v ^ ((v >> 6) & 7);
        async_cp16(gtile + s * 16, ltile + v * 16);
    }
    __syncthreads();   // drains vmcnt (compiler emits s_waitcnt vmcnt(0))

    // ---- Phase 2: gather 4 consecutive-t scalars per lane (swizzled addr),
    // coalesced float4 store along t. 64 c-rows x 25 float4/row per block. ----
    // For work item (c, j): ti = 4j..4j+3, swizzled column
    //   cs = (((c>>2) ^ (j&7)) << 2) | (c&3)   [same involution as phase 1]
    #pragma unroll
    for (int k = 0; k < 6; ++k) {
        const int i  = tid + k * 256;
        const int c  = i / 25;
        const int j  = i - c * 25;
        const int cs = ((((c >> 2) ^ (j & 7)) << 2) | (c & 3));
        const int tb = j << 2;
        float4 v;
        v.x = lds[(tb + 0) * CDIM + cs];
        v.y = lds[(tb + 1) * CDIM + cs];
        v.z = lds[(tb + 2) * CDIM + cs];
        v.w = lds[(tb + 3) * CDIM + cs];
        const size_t off = (size_t)(bw * CDIM + c) * TDIM + (t0 + tb);
        *(float4*)(out + off) = v;
    }
    if (tid < 64) {                              // tail items 1536..1599, wave 0
        const int i  = tid + 6 * 256;
        const int c  = i / 25;
        const int j  = i - c * 25;
        const int cs = ((((c >> 2) ^ (j & 7)) << 2) | (c & 3));
        const int tb = j << 2;
        float4 v;
        v.x = lds[(tb + 0) * CDIM + cs];
        v.y = lds[(tb + 1) * CDIM + cs];
        v.z = lds[(tb + 2) * CDIM + cs];
        v.w = lds[(tb + 3) * CDIM + cs];
        const size_t off = (size_t)(bw * CDIM + c) * TDIM + (t0 + tb);
        *(float4*)(out + off) = v;
    }

    // ---- Index outputs (tiny): block 0 only ----
    if (blockIdx.x == 0) {
        for (int i = tid; i < 320; i += 256) {
            out[PATCH_ELEMS + i]       = (float)(i / 5);  // channel_indices
            out[PATCH_ELEMS + 320 + i] = (float)(i % 5);  // time_indices
        }
    }
}

extern "C" void kernel_launch(void* const* d_in, const int* in_sizes, int n_in,
                              void* d_out, int out_size, void* d_ws, size_t ws_size,
                              hipStream_t stream) {
    const float* in = (const float*)d_in[0];
    float* out = (float*)d_out;
    dim3 grid(512 * NTILE);   // 512 (b,w) slices * 10 t-tiles
    dim3 block(256);
    labram_patcher_kernel<<<grid, block, 0, stream>>>(in, out);
}

// Round 2
// 232.489 us; speedup vs baseline: 1.0731x; 1.0508x over previous
//
#include <hip/hip_runtime.h>

// LaBramChannelPatcher: [B=16, W=32, T=1000, C=64] fp32 ->
//   patches [B, W, C*nt=320, P=200]  (== per-(b,w) transpose [T,C] -> [C,T])
//   channel_indices [320] = repeat(arange(64), 5)
//   time_indices    [320] = tile(arange(5), 64)
//
// Round-2 repartition: block = (bw, channel-quartet of 16 ch).
//  - Writes: each block owns a CONTIGUOUS 64 KB, 128B-aligned output region
//    (16 full rows x 4000 B). No partial cache lines shared across blocks/XCDs
//    -> no TCC read-modify-write on the store path (round-1 theory: RMW on
//    16B-offset 400B chunks split across XCDs throttled writes to 1.5 TB/s).
//  - Reads: [1000 t x 16 c] slab, 64 B contiguous per t-row, fully coalesced.
//  - LDS 64,000 B, word-XOR swizzle c' = c ^ ((t>>1)&15): phase-1 scatter and
//    phase-2 column gather are both exactly 2 lanes/bank (conflict-free).
//  - Phase 2: scalar dword stores, 64 lanes = 256 B contiguous per instr;
//    all line merges are block-internal (same XCD L2).

#define TDIM 1000
#define CDIM 64
#define CQ   16                 // channels per block
#define NCQ  4                  // CDIM / CQ
#define PATCH_ELEMS 32768000    // 16*32*320*200

__global__ __launch_bounds__(512) void labram_patcher_kernel(
    const float* __restrict__ in, float* __restrict__ out)
{
    __shared__ float lds[TDIM * CQ];   // 64,000 B; [t][c'] linear stride 16

    const int tid = threadIdx.x;
    const int cq  = blockIdx.x & (NCQ - 1);
    const int bw  = blockIdx.x >> 2;          // 0..511 (b*32 + w)

    // ---- Phase 1: reg-staged load of the [1000 x 16c] slab (64 KB),
    //      XOR-swizzled scatter into LDS. 4000 float4 units, 512 threads. ----
    const float4* gsrc = (const float4*)(in + (size_t)bw * (TDIM * CDIM) + cq * CQ);
    // unit i: t = i>>2 (row, global stride 16 units), u = i&3 (16B unit in row)

    float4 v[8];
    #pragma unroll
    for (int k = 0; k < 7; ++k) {             // i <= 3583 < 4000: no guard
        const int i = tid + k * 512;
        v[k] = gsrc[(i >> 2) * 16 + (i & 3)];
    }
    const int i7 = tid + 7 * 512;
    if (i7 < 4000)
        v[7] = gsrc[(i7 >> 2) * 16 + (i7 & 3)];

    #pragma unroll
    for (int k = 0; k < 8; ++k) {
        const int i = tid + k * 512;
        if (k < 7 || i < 4000) {
            const int t = i >> 2;
            const int u = i & 3;
            const int s = (t >> 1) & 15;
            const int b = t * CQ;
            lds[b + ((u * 4 + 0) ^ s)] = v[k].x;
            lds[b + ((u * 4 + 1) ^ s)] = v[k].y;
            lds[b + ((u * 4 + 2) ^ s)] = v[k].z;
            lds[b + ((u * 4 + 3) ^ s)] = v[k].w;
        }
    }
    __syncthreads();

    // ---- Phase 2: column gather (conflict-free swizzled scalar ds_read),
    //      scalar dword stores: 64 lanes x 4 B = 256 B contiguous per instr.
    //      Block's output region: contiguous 16000 floats, 64 KB aligned. ----
    const int w = tid >> 6;                   // wave 0..7 -> rows 2w, 2w+1
    const int l = tid & 63;
    float* dst = out + (size_t)bw * (CDIM * TDIM) + cq * (CQ * TDIM);

    #pragma unroll
    for (int rr = 0; rr < 2; ++rr) {
        const int r = w * 2 + rr;
        #pragma unroll
        for (int tb = 0; tb < TDIM; tb += 64) {
            const int t = tb + l;
            if (t < TDIM)                      // only the tb=960 chunk masks
                dst[r * TDIM + t] = lds[t * CQ + (r ^ ((t >> 1) & 15))];
        }
    }

    // ---- Index outputs (tiny): block 0 only ----
    if (blockIdx.x == 0 && tid < 320) {
        out[PATCH_ELEMS + tid]       = (float)(tid / 5);  // channel_indices
        out[PATCH_ELEMS + 320 + tid] = (float)(tid % 5);  // time_indices
    }
}

extern "C" void kernel_launch(void* const* d_in, const int* in_sizes, int n_in,
                              void* d_out, int out_size, void* d_ws, size_t ws_size,
                              hipStream_t stream) {
    const float* in = (const float*)d_in[0];
    float* out = (float*)d_out;
    dim3 grid(512 * NCQ);   // 512 (b,w) slices * 4 channel-quartets
    dim3 block(512);
    labram_patcher_kernel<<<grid, block, 0, stream>>>(in, out);
}